// Round 21
// baseline (244.772 us; speedup 1.0000x reference)
//
#include <hip/hip_runtime.h>
#include <math.h>

#define NROWS 2048
#define DDIM 32

typedef __attribute__((ext_vector_type(8))) short short8;  // 8 bf16
typedef __attribute__((ext_vector_type(4))) float f32x4;

__device__ __forceinline__ unsigned packbf(float a, float b) {
  // bf16(a) in low 16, bf16(b) in high 16 (truncation; lo-plane captures rest)
  return (__float_as_uint(a) >> 16) | (__float_as_uint(b) & 0xffff0000u);
}

// ---------------------------------------------------------------------------
// Single fused kernel. 128x128 tile per 512-thread block (8 waves, 2/SIMD).
// IDENTICAL to round 20 except __launch_bounds__(512, 1): the previous
// (512, 2) imposed a hard 128-VGPR cap (min-2-blocks/CU semantics) that
// force-spilled every variant needing >128 regs, while LDS (>100 KB) meant
// 2 blocks/CU could never co-reside anyway. With min-1-block the cap is 256.
// WAVE ROLE-SPLIT: waves 0-1 run the redundant stats stream (wave0=x,
// wave1=y; intra-wave shuffle reduce, no LDS/barriers), then join quantum
// late; waves 2-7 start quantum immediately. Stats' L2 traffic hides under
// quantum's LDS window (disjoint pipes).
// classical = exp(2*dot - nx - ny); quantum term = 0.5 + hcx*cy + hsx*sy.
// ---------------------------------------------------------------------------
__global__ __launch_bounds__(512, 1) void HybridKernel_fused(
    const float* __restrict__ x, const float* __restrict__ y,
    float* __restrict__ out) {
  __shared__ float4 sCS[2][16 * 128];   // 64 KB swizzled cos/sin pairs
  __shared__ uint4 sXB[2][2][128 * 5];  // 40 KB bf16 [side][hi/lo], 80B/row
  __shared__ float sNrm[2][128];
  __shared__ float sMu[2][32];
  __shared__ float sInv[2][32];

  const int t = threadIdx.x;
  const int i0 = blockIdx.y * 128;
  const int j0 = blockIdx.x * 128;

  // --- 1. hoist tile global loads ---
  float4 gx[2], gy[2];
#pragma unroll
  for (int rep = 0; rep < 2; ++rep) {
    const int u = t + 512 * rep;
    const int row = u >> 3;
    const int q = u & 7;
    gx[rep] = *reinterpret_cast<const float4*>(&x[(i0 + row) * DDIM + q * 4]);
    gy[rep] = *reinterpret_cast<const float4*>(&y[(j0 + row) * DDIM + q * 4]);
  }

  // --- 2. cs staging (raw values only) ---
#pragma unroll
  for (int rep = 0; rep < 2; ++rep) {
    const int u = t + 512 * rep;
    const int row = u >> 3;
    const int q = u & 7;
#pragma unroll
    for (int side = 0; side < 2; ++side) {
      const float4 g = side ? gy[rep] : gx[rep];
      const float sc = side ? 1.0f : 0.5f;
      const float gv[4] = {g.x, g.y, g.z, g.w};
      float hc[4], hs[4];
#pragma unroll
      for (int k = 0; k < 4; ++k) {
        float sn, cs;
        __sincosf(gv[k], &sn, &cs);
        hc[k] = sc * cs;
        hs[k] = sc * sn;
      }
      const int dp0 = 2 * q, dp1 = 2 * q + 1;
      sCS[side][dp0 * 128 + (row ^ (dp0 & 7))] =
          make_float4(hc[0], hs[0], hc[1], hs[1]);
      sCS[side][dp1 * 128 + (row ^ (dp1 & 7))] =
          make_float4(hc[2], hs[2], hc[3], hs[3]);
    }
  }
  __syncthreads();  // sCS complete before any wave's quantum reads

  // --- wave/lane geometry (MFMA C/D layout) ---
  const int w = t >> 6;
  const int l = t & 63;
  const int l4 = l >> 4;  // 0..3
  const int ln = l & 15;
  const int R0 = (w >> 1) * 32;  // wave row base
  const int C0 = (w & 1) * 64;   // wave col base

  int r_idx[8], c_idx[4];
#pragma unroll
  for (int ri = 0; ri < 8; ++ri)
    r_idx[ri] = R0 + 16 * (ri >> 2) + 4 * l4 + (ri & 3);
#pragma unroll
  for (int tc = 0; tc < 4; ++tc) c_idx[tc] = C0 + 16 * tc + ln;

  // --- 3a. stats (waves 0-1 only; wave0=x, wave1=y; no LDS, no barriers) ---
  if (t < 128) {
    const int wv = t >> 6;  // array select
    const f32x4* src = reinterpret_cast<const f32x4*>(wv ? y : x) + l;
    f32x4 S = {0.f, 0.f, 0.f, 0.f}, Q = {0.f, 0.f, 0.f, 0.f};
#pragma unroll 8
    for (int i = 0; i < 256; ++i) {  // lane l covers f4 index l + 64*i
      const f32x4 v = src[(size_t)i * 64];
      S += v;
      Q = __builtin_elementwise_fma(v, v, Q);
    }
    // butterfly over the rg bits (lanes at stride 8 share a column quad)
#pragma unroll
    for (int m = 8; m <= 32; m <<= 1) {
#pragma unroll
      for (int k = 0; k < 4; ++k) {
        S[k] += __shfl_xor(S[k], m);
        Q[k] += __shfl_xor(Q[k], m);
      }
    }
    if ((l >> 3) == 0) {  // lanes 0..7: finalize cols 4cq..4cq+3
      const int cq = l & 7;
      const float n = (float)NROWS;
#pragma unroll
      for (int k = 0; k < 4; ++k) {
        const float mean = S[k] / n;
        const float var = fmaxf((Q[k] - S[k] * mean) / (n - 1.f), 0.f);
        sMu[wv][cq * 4 + k] = mean;
        sInv[wv][cq * 4 + k] = 1.f / (sqrtf(var) + 1e-8f);
      }
    }
  }

  // --- 3b. quantum: 16 phases (all waves; waves 2-7 start immediately) ---
  const float4* sCS0 = &sCS[0][0];
  const float4* sCS1 = &sCS[1][0];
  float qp[8][4];
#pragma unroll
  for (int ri = 0; ri < 8; ++ri)
#pragma unroll
    for (int tc = 0; tc < 4; ++tc) qp[ri][tc] = 1.f;

#pragma unroll
  for (int dp = 0; dp < 16; ++dp) {
    const int sw = dp & 7;
    const int base = dp * 128;
    float4 FX[8], FY[4];
#pragma unroll
    for (int ri = 0; ri < 8; ++ri) FX[ri] = sCS0[base + (r_idx[ri] ^ sw)];
#pragma unroll
    for (int tc = 0; tc < 4; ++tc) FY[tc] = sCS1[base + (c_idx[tc] ^ sw)];
#pragma unroll
    for (int ri = 0; ri < 8; ++ri)
#pragma unroll
      for (int tc = 0; tc < 4; ++tc) {
        const float t0 =
            fmaf(FX[ri].x, FY[tc].x, fmaf(FX[ri].y, FY[tc].y, 0.5f));
        const float t1 =
            fmaf(FX[ri].z, FY[tc].z, fmaf(FX[ri].w, FY[tc].w, 0.5f));
        qp[ri][tc] *= t0 * t1;
      }
  }
  __syncthreads();  // sMu/sInv visible to all; everyone done with phase A

  // --- 4. bf16 hi/lo staging + row norms (all waves) ---
#pragma unroll
  for (int rep = 0; rep < 2; ++rep) {
    const int u = t + 512 * rep;
    const int row = u >> 3;
    const int q = u & 7;
#pragma unroll
    for (int side = 0; side < 2; ++side) {
      const float4 g = side ? gy[rep] : gx[rep];
      const float gv[4] = {g.x, g.y, g.z, g.w};
      float xn[4];
      float nrm = 0.f;
#pragma unroll
      for (int k = 0; k < 4; ++k) {
        const int d = q * 4 + k;
        xn[k] = (gv[k] - sMu[side][d]) * sInv[side][d];
        nrm = fmaf(xn[k], xn[k], nrm);
      }
      float hif[4], lof[4];
#pragma unroll
      for (int k = 0; k < 4; ++k) {
        hif[k] = __uint_as_float(__float_as_uint(xn[k]) & 0xffff0000u);
        lof[k] = xn[k] - hif[k];
      }
      char* bh = (char*)&sXB[side][0][0] + row * 80 + q * 8;
      char* bl = (char*)&sXB[side][1][0] + row * 80 + q * 8;
      *reinterpret_cast<uint2*>(bh) =
          make_uint2(packbf(hif[0], hif[1]), packbf(hif[2], hif[3]));
      *reinterpret_cast<uint2*>(bl) =
          make_uint2(packbf(lof[0], lof[1]), packbf(lof[2], lof[3]));
      nrm += __shfl_xor(nrm, 1);
      nrm += __shfl_xor(nrm, 2);
      nrm += __shfl_xor(nrm, 4);
      if ((t & 7) == 0) sNrm[side][row] = nrm;
    }
  }
  __syncthreads();

  // --- 5. classical via MFMA: 2x4 tiles, hi/lo 3-pass ---
  short8 Ah[2], Al[2], Bh[4], Bl[4];
  {
    const char* bxh = (const char*)&sXB[0][0][0];
    const char* bxl = (const char*)&sXB[0][1][0];
    const char* byh = (const char*)&sXB[1][0][0];
    const char* byl = (const char*)&sXB[1][1][0];
#pragma unroll
    for (int tr = 0; tr < 2; ++tr) {
      const int off = (R0 + 16 * tr + ln) * 80 + l4 * 16;
      Ah[tr] = *reinterpret_cast<const short8*>(bxh + off);
      Al[tr] = *reinterpret_cast<const short8*>(bxl + off);
    }
#pragma unroll
    for (int tc = 0; tc < 4; ++tc) {
      const int off = (C0 + 16 * tc + ln) * 80 + l4 * 16;
      Bh[tc] = *reinterpret_cast<const short8*>(byh + off);
      Bl[tc] = *reinterpret_cast<const short8*>(byl + off);
    }
  }
  f32x4 dotacc[2][4];
#pragma unroll
  for (int tr = 0; tr < 2; ++tr)
#pragma unroll
    for (int tc = 0; tc < 4; ++tc) {
      f32x4 a = {0.f, 0.f, 0.f, 0.f};
      a = __builtin_amdgcn_mfma_f32_16x16x32_bf16(Ah[tr], Bl[tc], a, 0, 0, 0);
      a = __builtin_amdgcn_mfma_f32_16x16x32_bf16(Al[tr], Bh[tc], a, 0, 0, 0);
      a = __builtin_amdgcn_mfma_f32_16x16x32_bf16(Ah[tr], Bh[tc], a, 0, 0, 0);
      dotacc[tr][tc] = a;
    }

  // --- 6. classical epilogue + combine + store ---
#pragma unroll
  for (int tr = 0; tr < 2; ++tr) {
#pragma unroll
    for (int mm = 0; mm < 4; ++mm) {
      const int ri = tr * 4 + mm;
      const float nx = sNrm[0][r_idx[ri]];
      float* o = out + (size_t)(i0 + r_idx[ri]) * NROWS + j0;
#pragma unroll
      for (int tc = 0; tc < 4; ++tc) {
        const float ny = sNrm[1][c_idx[tc]];
        const float cl = __expf(2.f * dotacc[tr][tc][mm] - nx - ny);
        o[c_idx[tc]] = 0.5f * (cl + qp[ri][tc]);
      }
    }
  }
}

extern "C" void kernel_launch(void* const* d_in, const int* in_sizes, int n_in,
                              void* d_out, int out_size, void* d_ws,
                              size_t ws_size, hipStream_t stream) {
  const float* x = (const float*)d_in[0];
  const float* y = (const float*)d_in[1];
  float* out = (float*)d_out;

  dim3 grid(NROWS / 128, NROWS / 128);
  HybridKernel_fused<<<grid, 512, 0, stream>>>(x, y, out);
}

// Round 22
// 23.763 us; speedup vs baseline: 10.3006x; 10.3006x over previous
//
#include <hip/hip_runtime.h>
#include <math.h>

#define NROWS 2048
#define DDIM 32

typedef __attribute__((ext_vector_type(8))) short short8;  // 8 bf16
typedef __attribute__((ext_vector_type(4))) float f32x4;

__device__ __forceinline__ unsigned packbf(float a, float b) {
  // bf16(a) in low 16, bf16(b) in high 16 (truncation; lo-plane captures rest)
  return (__float_as_uint(a) >> 16) | (__float_as_uint(b) & 0xffff0000u);
}

// ---------------------------------------------------------------------------
// Single fused kernel (r14 champion, restored verbatim).
// 128x128 tile per 512-thread block (8 waves, 2/SIMD).
// Phase order: tile loads -> cs staging (raw x) -> redundant per-block
//   full-input stats (L2-resident streaming) -> reduce -> bf16 hi/lo staging
//   + row norms -> MFMA classical (bf16 hi/lo 3-pass, ~1e-6 exact) ->
//   quantum on VALU (16 phases, 12 XOR-swizzled ds_read_b128 each) ->
//   combine -> store.
// Quantum runs in MFMA C/D layout (col=lane&15, row=4*(lane>>4)+reg).
// classical = exp(2*dot - nx - ny); quantum term = 0.5 + hcx*cy + hsx*sy.
// NOTE: this structure sits at a codegen cliff — adding loop-carried state
// or reordering accumulator lifetimes (r15-r21) triggers scratch spill
// (VGPR clamp 128 + ~400MB scratch traffic). Do not perturb.
// ---------------------------------------------------------------------------
__global__ __launch_bounds__(512, 2) void HybridKernel_fused(
    const float* __restrict__ x, const float* __restrict__ y,
    float* __restrict__ out) {
  __shared__ float4 sCS[2][16 * 128];   // 64 KB swizzled cos/sin pairs
  __shared__ uint4 sXB[2][2][128 * 5];  // 40 KB bf16 [side][hi/lo], 80B/row
  __shared__ f32x4 sRed[2][64][8];      // 16 KB stats partials (sum)
  __shared__ f32x4 sRedQ[2][64][8];     // 16 KB stats partials (sumsq)
  __shared__ float sNrm[2][128];
  __shared__ float sMu[2][32];
  __shared__ float sInv[2][32];

  const int t = threadIdx.x;
  const int i0 = blockIdx.y * 128;
  const int j0 = blockIdx.x * 128;

  // --- 1. hoist tile global loads ---
  float4 gx[2], gy[2];
#pragma unroll
  for (int rep = 0; rep < 2; ++rep) {
    const int u = t + 512 * rep;
    const int row = u >> 3;
    const int q = u & 7;
    gx[rep] = *reinterpret_cast<const float4*>(&x[(i0 + row) * DDIM + q * 4]);
    gy[rep] = *reinterpret_cast<const float4*>(&y[(j0 + row) * DDIM + q * 4]);
  }

  // --- 2. cs staging (needs only raw values) ---
#pragma unroll
  for (int rep = 0; rep < 2; ++rep) {
    const int u = t + 512 * rep;
    const int row = u >> 3;
    const int q = u & 7;
#pragma unroll
    for (int side = 0; side < 2; ++side) {
      const float4 g = side ? gy[rep] : gx[rep];
      const float sc = side ? 1.0f : 0.5f;
      const float gv[4] = {g.x, g.y, g.z, g.w};
      float hc[4], hs[4];
#pragma unroll
      for (int k = 0; k < 4; ++k) {
        float sn, cs;
        __sincosf(gv[k], &sn, &cs);
        hc[k] = sc * cs;
        hs[k] = sc * sn;
      }
      const int dp0 = 2 * q, dp1 = 2 * q + 1;
      sCS[side][dp0 * 128 + (row ^ (dp0 & 7))] =
          make_float4(hc[0], hs[0], hc[1], hs[1]);
      sCS[side][dp1 * 128 + (row ^ (dp1 & 7))] =
          make_float4(hc[2], hs[2], hc[3], hs[3]);
    }
  }

  // --- 3. stats streaming: thread covers colquad cq, rows rg+64*i ---
  {
    const int cq = t & 7;
    const int rg = t >> 3;  // 0..63
    const f32x4* px = reinterpret_cast<const f32x4*>(x) + rg * 8 + cq;
    const f32x4* py = reinterpret_cast<const f32x4*>(y) + rg * 8 + cq;
    f32x4 sx = {0.f, 0.f, 0.f, 0.f}, qx = {0.f, 0.f, 0.f, 0.f};
    f32x4 sy = {0.f, 0.f, 0.f, 0.f}, qy = {0.f, 0.f, 0.f, 0.f};
#pragma unroll 4
    for (int i = 0; i < NROWS / 64; ++i) {  // 32 iters
      const f32x4 vx = px[(size_t)i * 64 * 8];
      const f32x4 vy = py[(size_t)i * 64 * 8];
      sx += vx;
      qx = __builtin_elementwise_fma(vx, vx, qx);
      sy += vy;
      qy = __builtin_elementwise_fma(vy, vy, qy);
    }
    sRed[0][rg][cq] = sx;
    sRedQ[0][rg][cq] = qx;
    sRed[1][rg][cq] = sy;
    sRedQ[1][rg][cq] = qy;
  }
  __syncthreads();
  if (t < 128) {
    const int a = t >> 6;
    const int g8 = (t >> 3) & 7;
    const int cq2 = t & 7;
    f32x4 S = {0.f, 0.f, 0.f, 0.f}, Q = {0.f, 0.f, 0.f, 0.f};
#pragma unroll
    for (int k = 0; k < 8; ++k) {
      S += sRed[a][g8 * 8 + k][cq2];
      Q += sRedQ[a][g8 * 8 + k][cq2];
    }
    sRed[a][g8][cq2] = S;
    sRedQ[a][g8][cq2] = Q;
  }
  __syncthreads();
  if (t < 16) {  // t = a*8 + cq
    const int a = t >> 3;
    const int cq2 = t & 7;
    f32x4 S = {0.f, 0.f, 0.f, 0.f}, Q = {0.f, 0.f, 0.f, 0.f};
#pragma unroll
    for (int k = 0; k < 8; ++k) {
      S += sRed[a][k][cq2];
      Q += sRedQ[a][k][cq2];
    }
    const float n = (float)NROWS;
#pragma unroll
    for (int k = 0; k < 4; ++k) {
      const float mean = S[k] / n;
      const float var = fmaxf((Q[k] - S[k] * mean) / (n - 1.f), 0.f);
      sMu[a][cq2 * 4 + k] = mean;
      sInv[a][cq2 * 4 + k] = 1.f / (sqrtf(var) + 1e-8f);
    }
  }
  __syncthreads();

  // --- 4. bf16 hi/lo staging + row norms (needs stats) ---
#pragma unroll
  for (int rep = 0; rep < 2; ++rep) {
    const int u = t + 512 * rep;
    const int row = u >> 3;
    const int q = u & 7;
#pragma unroll
    for (int side = 0; side < 2; ++side) {
      const float4 g = side ? gy[rep] : gx[rep];
      const float gv[4] = {g.x, g.y, g.z, g.w};
      float xn[4];
      float nrm = 0.f;
#pragma unroll
      for (int k = 0; k < 4; ++k) {
        const int d = q * 4 + k;
        xn[k] = (gv[k] - sMu[side][d]) * sInv[side][d];
        nrm = fmaf(xn[k], xn[k], nrm);
      }
      float hif[4], lof[4];
#pragma unroll
      for (int k = 0; k < 4; ++k) {
        hif[k] = __uint_as_float(__float_as_uint(xn[k]) & 0xffff0000u);
        lof[k] = xn[k] - hif[k];
      }
      char* bh = (char*)&sXB[side][0][0] + row * 80 + q * 8;
      char* bl = (char*)&sXB[side][1][0] + row * 80 + q * 8;
      *reinterpret_cast<uint2*>(bh) =
          make_uint2(packbf(hif[0], hif[1]), packbf(hif[2], hif[3]));
      *reinterpret_cast<uint2*>(bl) =
          make_uint2(packbf(lof[0], lof[1]), packbf(lof[2], lof[3]));
      nrm += __shfl_xor(nrm, 1);
      nrm += __shfl_xor(nrm, 2);
      nrm += __shfl_xor(nrm, 4);
      if ((t & 7) == 0) sNrm[side][row] = nrm;
    }
  }
  __syncthreads();

  // --- wave/lane geometry (MFMA C/D layout) ---
  const int w = t >> 6;
  const int l = t & 63;
  const int l4 = l >> 4;  // 0..3
  const int ln = l & 15;
  const int R0 = (w >> 1) * 32;  // wave row base
  const int C0 = (w & 1) * 64;   // wave col base

  int r_idx[8], c_idx[4];
#pragma unroll
  for (int ri = 0; ri < 8; ++ri)
    r_idx[ri] = R0 + 16 * (ri >> 2) + 4 * l4 + (ri & 3);
#pragma unroll
  for (int tc = 0; tc < 4; ++tc) c_idx[tc] = C0 + 16 * tc + ln;

  // --- 5. classical via MFMA: 2x4 tiles, hi/lo 3-pass ---
  short8 Ah[2], Al[2], Bh[4], Bl[4];
  {
    const char* bxh = (const char*)&sXB[0][0][0];
    const char* bxl = (const char*)&sXB[0][1][0];
    const char* byh = (const char*)&sXB[1][0][0];
    const char* byl = (const char*)&sXB[1][1][0];
#pragma unroll
    for (int tr = 0; tr < 2; ++tr) {
      const int off = (R0 + 16 * tr + ln) * 80 + l4 * 16;
      Ah[tr] = *reinterpret_cast<const short8*>(bxh + off);
      Al[tr] = *reinterpret_cast<const short8*>(bxl + off);
    }
#pragma unroll
    for (int tc = 0; tc < 4; ++tc) {
      const int off = (C0 + 16 * tc + ln) * 80 + l4 * 16;
      Bh[tc] = *reinterpret_cast<const short8*>(byh + off);
      Bl[tc] = *reinterpret_cast<const short8*>(byl + off);
    }
  }
  f32x4 dotacc[2][4];
#pragma unroll
  for (int tr = 0; tr < 2; ++tr)
#pragma unroll
    for (int tc = 0; tc < 4; ++tc) {
      f32x4 a = {0.f, 0.f, 0.f, 0.f};
      a = __builtin_amdgcn_mfma_f32_16x16x32_bf16(Ah[tr], Bl[tc], a, 0, 0, 0);
      a = __builtin_amdgcn_mfma_f32_16x16x32_bf16(Al[tr], Bh[tc], a, 0, 0, 0);
      a = __builtin_amdgcn_mfma_f32_16x16x32_bf16(Ah[tr], Bh[tc], a, 0, 0, 0);
      dotacc[tr][tc] = a;
    }

  // --- 6. quantum: 16 phases on VALU, same (row,col) ownership ---
  const float4* sCS0 = &sCS[0][0];
  const float4* sCS1 = &sCS[1][0];
  float qp[8][4];
#pragma unroll
  for (int ri = 0; ri < 8; ++ri)
#pragma unroll
    for (int tc = 0; tc < 4; ++tc) qp[ri][tc] = 1.f;

#pragma unroll
  for (int dp = 0; dp < 16; ++dp) {
    const int sw = dp & 7;
    float4 FX[8], FY[4];
#pragma unroll
    for (int ri = 0; ri < 8; ++ri) FX[ri] = sCS0[dp * 128 + (r_idx[ri] ^ sw)];
#pragma unroll
    for (int tc = 0; tc < 4; ++tc) FY[tc] = sCS1[dp * 128 + (c_idx[tc] ^ sw)];
#pragma unroll
    for (int ri = 0; ri < 8; ++ri)
#pragma unroll
      for (int tc = 0; tc < 4; ++tc) {
        const float t0 =
            fmaf(FX[ri].x, FY[tc].x, fmaf(FX[ri].y, FY[tc].y, 0.5f));
        const float t1 =
            fmaf(FX[ri].z, FY[tc].z, fmaf(FX[ri].w, FY[tc].w, 0.5f));
        qp[ri][tc] *= t0 * t1;
      }
  }

  // --- 7. classical epilogue + combine + store ---
#pragma unroll
  for (int tr = 0; tr < 2; ++tr) {
#pragma unroll
    for (int mm = 0; mm < 4; ++mm) {
      const int ri = tr * 4 + mm;
      const float nx = sNrm[0][r_idx[ri]];
      float* o = out + (size_t)(i0 + r_idx[ri]) * NROWS + j0;
#pragma unroll
      for (int tc = 0; tc < 4; ++tc) {
        const float ny = sNrm[1][c_idx[tc]];
        const float cl = __expf(2.f * dotacc[tr][tc][mm] - nx - ny);
        o[c_idx[tc]] = 0.5f * (cl + qp[ri][tc]);
      }
    }
  }
}

extern "C" void kernel_launch(void* const* d_in, const int* in_sizes, int n_in,
                              void* d_out, int out_size, void* d_ws,
                              size_t ws_size, hipStream_t stream) {
  const float* x = (const float*)d_in[0];
  const float* y = (const float*)d_in[1];
  float* out = (float*)d_out;

  dim3 grid(NROWS / 128, NROWS / 128);
  HybridKernel_fused<<<grid, 512, 0, stream>>>(x, y, out);
}